// Round 2
// baseline (2837.932 us; speedup 1.0000x reference)
//
#include <hip/hip_runtime.h>
#include <stdint.h>

typedef unsigned short ushort_t;
typedef __attribute__((ext_vector_type(8))) short short8;
typedef __attribute__((ext_vector_type(4))) float float4v;
typedef __attribute__((ext_vector_type(4))) int int4v;

#define TSTEPS 512
#define NBATCH 128
#define HID 256
#define NIN 64
#define RB 32           // ring depth (steps)
#define NBHID (NBATCH*HID)
#define RING_DW (RB*NBHID)                         // 1,048,576 dwords per ring

// workspace layout (bytes) — ring is now f32-tagged, same byte size as before
#define OFF_FLAGS   0u
#define OFF_BIAS    4096u
#define OFF_H1R     16384u
#define RING_BYTES  (RB*(unsigned)NBATCH*HID*4u)   // 4,194,304
#define OFF_H2R     (OFF_H1R + RING_BYTES)
#define OFF_WF1     (OFF_H2R + RING_BYTES)
#define WF1_FRAGS   (16*8*4*4)                     // 2048 fragments of 1KB
#define OFF_WF2     (OFF_WF1 + WF1_FRAGS*1024u)
#define WF2_FRAGS   (16*8*6*4)                     // 3072 fragments of 1KB
#define OFF_HOUT    (OFF_WF2 + WF2_FRAGS*1024u)    // 128*256 fp32 = 128KB

// Ring element: f32 h-value with low 5 mantissa bits replaced by a generation tag.
//   live tags  : gen = t>>5  (0..15, unique across the 512-step run)
//   prefill    : tag 31 (the t = -1 zero state; matches ((unsigned)(-1)>>5)&31)
//   invalid    : tag 16 (prep_misc wipes the whole ring each run -> no cross-run alias)
// Tag and data share one dword => a single load is atomic: tag match ==> data valid.

__device__ __forceinline__ ushort_t bf16h(float f) {
    unsigned u = __float_as_uint(f);
    u += 0x7fffu + ((u >> 16) & 1u);
    return (ushort_t)(u >> 16);
}
__device__ __forceinline__ float bf16f(ushort_t h) {
    return __uint_as_float(((unsigned)h) << 16);
}

// ---- IC-coherent (device-wide) access helpers: sc0 sc1 ----

__device__ __forceinline__ int ld_cg_i32(const void* p) {
    int r;
    asm volatile("global_load_dword %0, %1, off sc0 sc1\n\ts_waitcnt vmcnt(0)"
                 : "=v"(r) : "v"(p) : "memory");
    return r;
}
__device__ __forceinline__ float ld_cg_f32(const void* p) {
    float r;
    asm volatile("global_load_dword %0, %1, off sc0 sc1\n\ts_waitcnt vmcnt(0)"
                 : "=v"(r) : "v"(p) : "memory");
    return r;
}
__device__ __forceinline__ void ld_cg_x2(int4v& a, int4v& b, const void* pa, const void* pb) {
    asm volatile("global_load_dwordx4 %0, %2, off sc0 sc1\n\t"
                 "global_load_dwordx4 %1, %3, off sc0 sc1\n\t"
                 "s_waitcnt vmcnt(0)"
                 : "=&v"(a), "=&v"(b)
                 : "v"(pa), "v"(pb) : "memory");
}
__device__ __forceinline__ void ld_cg_x4(int4v& a, int4v& b, int4v& c, int4v& d,
                                         const void* pa, const void* pb,
                                         const void* pc, const void* pd) {
    asm volatile("global_load_dwordx4 %0, %4, off sc0 sc1\n\t"
                 "global_load_dwordx4 %1, %5, off sc0 sc1\n\t"
                 "global_load_dwordx4 %2, %6, off sc0 sc1\n\t"
                 "global_load_dwordx4 %3, %7, off sc0 sc1\n\t"
                 "s_waitcnt vmcnt(0)"
                 : "=&v"(a), "=&v"(b), "=&v"(c), "=&v"(d)
                 : "v"(pa), "v"(pb), "v"(pc), "v"(pd) : "memory");
}
__device__ __forceinline__ void st_cg_u32(void* p, unsigned v) {
    asm volatile("global_store_dword %0, %1, off sc0 sc1" :: "v"(p), "v"(v) : "memory");
}
__device__ __forceinline__ void st_cg_i32(int* p, int v) {
    asm volatile("global_store_dword %0, %1, off sc0 sc1" :: "v"(p), "v"(v) : "memory");
}
__device__ __forceinline__ void st_cg_f32(void* p, float v) {
    asm volatile("global_store_dword %0, %1, off sc0 sc1" :: "v"(p), "v"(v) : "memory");
}

// all 8 dwords carry the expected generation tag?
__device__ __forceinline__ bool tags8_ok(int4v a, int4v b, unsigned eg) {
    return (((unsigned)a[0] & 31u) == eg) & (((unsigned)a[1] & 31u) == eg) &
           (((unsigned)a[2] & 31u) == eg) & (((unsigned)a[3] & 31u) == eg) &
           (((unsigned)b[0] & 31u) == eg) & (((unsigned)b[1] & 31u) == eg) &
           (((unsigned)b[2] & 31u) == eg) & (((unsigned)b[3] & 31u) == eg);
}

// strip tags, split 8 f32 into bf16 hi/lo planes, store to LDS
__device__ __forceinline__ void emit_hilo8(int4v d0, int4v d1, ushort_t* pA, ushort_t* pB) {
    union { ushort_t u[8]; int4v v4; } hiP, loP;
    #pragma unroll
    for (int z = 0; z < 8; z++) {
        unsigned u = ((unsigned)(z < 4 ? d0[z] : d1[z - 4])) & ~31u;
        float f = __uint_as_float(u);
        ushort_t hi = bf16h(f);
        hiP.u[z] = hi;
        loP.u[z] = bf16h(f - bf16f(hi));
    }
    *(int4v*)pA = hiP.v4;
    *(int4v*)pB = loP.v4;
}

// ---------------- prep kernels ----------------

__global__ void prep_misc(const float* bxh1, const float* bhh1,
                          const float* bxh2, const float* bhh2,
                          float* bias, int* flags, unsigned* h1r, unsigned* h2r)
{
    int n = blockIdx.x * blockDim.x + threadIdx.x;
    if (n < 1024)       bias[n] = bxh1[n] + bhh1[n];
    else if (n < 2048)  bias[n] = bxh2[n - 1024] + bhh2[n - 1024];
    else if (n < 2304)  flags[n - 2048] = 0;
    else {
        int d = n - 2304;
        if (d < 2 * RING_DW) {
            unsigned* ring = (d < RING_DW) ? h1r : h2r;
            int e = (d < RING_DW) ? d : d - RING_DW;
            int slot = e >> 15;                    // / NBHID (32768)
            ring[e] = (slot == RB - 1) ? 0x1Fu : 0x10u;  // t=-1 zeros (tag 31) / invalid (16)
        }
    }
}

// Build MFMA B-fragments (hi/lo split weights) in exact consumption order:
// fragment id = ((slice*8 + wave)*F + i)*4 + ntile ; each fragment = [lane][8] bf16.
__global__ void prep_wf(const float* Wxh1, const float* Whh1,
                        const float* Wxh2, const float* Whh2,
                        ushort_t* wf1, ushort_t* wf2)
{
    int n = blockIdx.x * blockDim.x + threadIdx.x;
    const int L1E = WF1_FRAGS * 512;
    const int L2E = WF2_FRAGS * 512;
    if (n >= L1E + L2E) return;
    int layer = (n >= L1E) ? 1 : 0;
    int e = layer ? (n - L1E) : n;
    int el = e & 511;
    int f  = e >> 9;
    int lane = el >> 3, j = el & 7;
    int nt = f & 3;
    int rem = f >> 2;
    int i, wv, slice, F, S;
    if (!layer) { F = 4; S = 10; i = rem & 3; wv = (rem >> 2) & 7; slice = rem >> 5; }
    else        { F = 6; S = 16; i = rem % 6; int r2 = rem / 6; wv = r2 & 7; slice = r2 >> 3; }
    int fg = wv * F + i;
    int col = lane & 15;
    int row = nt * 256 + slice * 16 + col;
    float val = 0.f;
    if (fg < 3 * S) {
        int sec = (fg < S) ? 0 : ((fg < 2 * S) ? 1 : 2);
        int ks = (fg - sec * S) * 32 + (lane >> 4) * 8 + j;
        float w;
        if (!layer) w = (ks < 256) ? Whh1[row * 256 + ks] : Wxh1[row * 64 + (ks - 256)];
        else        w = (ks < 256) ? Wxh2[row * 256 + ks] : Whh2[row * 256 + (ks - 256)];
        ushort_t hi = bf16h(w);
        val = (sec < 2) ? bf16f(hi) : (w - bf16f(hi));
    }
    (layer ? wf2 : wf1)[e] = bf16h(val);
}

// ---------------- recurrent kernel ----------------
// grid = 256 WGs x 512 threads. blockIdx%8 = batch group, blockIdx/8: [0,16) layer1
// slice, [16,32) layer2 slice. Cross-WG handoff: tagged f32 ring through IC.
// Consumers spin on the data itself (tag in the same dword); producers never drain.

template<int LAYER, int F, int S, int PITCH>
__device__ __forceinline__ void run_layer(
    int g, int slice, int tid, const float* __restrict__ x,
    int* flags, const float* bias,
    unsigned* h1r, unsigned* h2r, const ushort_t* wfrag, float* hOut,
    ushort_t* sA, ushort_t* sB, float (*red)[4][64][4])
{
    const int wv = tid >> 6, lane = tid & 63;
    const int mrow = lane & 15, q = lane >> 4;
    int* p1 = flags + g * 16;            // layer1 WG progress (published step)
    int* p2 = flags + 128 + g * 16;      // layer2 WG progress
    int* myflag = flags + LAYER * 128 + g * 16 + slice;

    // persistent B fragments in VGPRs
    short8 bw[4][F];
    {
        const ushort_t* base = wfrag + (size_t)((slice * 8 + wv) * F) * 4 * 512;
        #pragma unroll
        for (int i = 0; i < F; i++)
            #pragma unroll
            for (int nt = 0; nt < 4; nt++)
                bw[nt][i] = *(const short8*)(base + (i * 4 + nt) * 512 + lane * 8);
    }

    float bs[4];
    #pragma unroll
    for (int nt = 0; nt < 4; nt++)
        bs[nt] = bias[LAYER * 1024 + nt * 256 + slice * 16 + mrow];

    float cst[4] = {0,0,0,0}, mst[4] = {0,0,0,0}, nst[4] = {0,0,0,0};

    for (int t = 0; t < TSTEPS; t++) {
        // ---- x staging (layer1, waves 2-3; off critical path) ----
        if (LAYER == 0 && tid >= 128 && tid < 256) {
            int idx = tid - 128;          // 0..127
            int r = idx >> 3, o = idx & 7;
            const float* xsrc = x + ((size_t)(g * 16 + r) * TSTEPS + t) * NIN + o * 8;
            float4v x0 = *(const float4v*)xsrc;
            float4v x1 = *(const float4v*)(xsrc + 4);
            float xs[8] = {x0[0], x0[1], x0[2], x0[3], x1[0], x1[1], x1[2], x1[3]};
            union { ushort_t u[8]; int4v v4; } hiP, loP;
            #pragma unroll
            for (int z = 0; z < 8; z++) {
                ushort_t hi = bf16h(xs[z]);
                hiP.u[z] = hi;
                loP.u[z] = bf16h(xs[z] - bf16f(hi));
            }
            *(int4v*)(sA + r * PITCH + (32 + o) * 8) = hiP.v4;
            *(int4v*)(sB + r * PITCH + (32 + o) * 8) = loP.v4;
        }

        // ---- ring backpressure check (wave0, every 8 steps, normally non-blocking) ----
        if ((t & 7) == 0 && t >= 32 && tid < 64) {
            int thr = t - 24;
            int* p = nullptr;
            if (LAYER == 0) {
                if (lane < 16)      p = p1 + lane;          // layer1 peers consume h1
                else if (lane < 32) p = p2 + (lane - 16);   // layer2 consumes h1
            } else {
                if (lane < 16)      p = p2 + lane;          // layer2 peers consume h2
            }
            if (p)
                while (ld_cg_i32(p) < thr) { }
        }

        // ---- stage h K-vectors: spin on tagged ring data, split to LDS ----
        {
            int r = tid >> 5, k = tid & 31;
            int row = g * 16 + r;
            if (LAYER == 0) {
                int slot = (t - 1) & (RB - 1);
                unsigned eg = ((unsigned)(t - 1) >> 5) & 31u;   // t=0 -> 31 (prefill zeros)
                const unsigned* base = h1r + ((size_t)slot * NBATCH + row) * HID + k * 8;
                int4v d0, d1;
                for (;;) {
                    ld_cg_x2(d0, d1, base, base + 4);
                    if (tags8_ok(d0, d1, eg)) break;
                }
                emit_hilo8(d0, d1, sA + r * PITCH + k * 8, sB + r * PITCH + k * 8);
            } else {
                int s1 = t & (RB - 1), s2 = (t - 1) & (RB - 1);
                unsigned e1 = ((unsigned)t >> 5) & 31u;
                unsigned e2 = ((unsigned)(t - 1) >> 5) & 31u;   // t=0 -> 31 (prefill zeros)
                const unsigned* b1 = h1r + ((size_t)s1 * NBATCH + row) * HID + k * 8;
                const unsigned* b2 = h2r + ((size_t)s2 * NBATCH + row) * HID + k * 8;
                int4v d0, d1, d2, d3;
                for (;;) {
                    ld_cg_x4(d0, d1, d2, d3, b1, b1 + 4, b2, b2 + 4);
                    if (tags8_ok(d0, d1, e1) && tags8_ok(d2, d3, e2)) break;
                }
                emit_hilo8(d0, d1, sA + r * PITCH + k * 8,        sB + r * PITCH + k * 8);
                emit_hilo8(d2, d3, sA + r * PITCH + (32 + k) * 8, sB + r * PITCH + (32 + k) * 8);
            }
        }
        __syncthreads();

        // ---- progress publish (lazy, off critical path) ----
        if (tid == 0 && (t & 7) == 0)
            st_cg_i32(myflag, t);

        // ---- MFMA: this wave's K-chunks across the 4 gate N-tiles ----
        float4v acc[4] = {};
        #pragma unroll
        for (int i = 0; i < F; i++) {
            const int fg = wv * F + i;
            short8 a;
            if (fg < 3 * S) {
                int sec = (fg >= S && fg < 2 * S) ? 1 : 0;
                int ks = ((fg < S) ? fg : ((fg < 2 * S) ? fg - S : fg - 2 * S)) * 32;
                const ushort_t* ap = (sec ? sB : sA) + mrow * PITCH + ks + q * 8;
                a = *(const short8*)ap;
            } else {
                a = (short8){0,0,0,0,0,0,0,0};
            }
            #pragma unroll
            for (int nt = 0; nt < 4; nt++)
                acc[nt] = __builtin_amdgcn_mfma_f32_16x16x32_bf16(a, bw[nt][i], acc[nt], 0, 0, 0);
        }

        // ---- cross-wave tree reduction (lane-major layout: conflict-free) ----
        if (wv >= 4) {
            #pragma unroll
            for (int nt = 0; nt < 4; nt++) *(float4v*)red[wv][nt][lane] = acc[nt];
        }
        __syncthreads();
        if (wv < 4) {
            #pragma unroll
            for (int nt = 0; nt < 4; nt++) acc[nt] += *(const float4v*)red[wv + 4][nt][lane];
            if (wv >= 2) {
                #pragma unroll
                for (int nt = 0; nt < 4; nt++) *(float4v*)red[wv][nt][lane] = acc[nt];
            }
        }
        __syncthreads();
        if (wv < 2) {
            #pragma unroll
            for (int nt = 0; nt < 4; nt++) acc[nt] += *(const float4v*)red[wv + 2][nt][lane];
            if (wv == 1) {
                #pragma unroll
                for (int nt = 0; nt < 4; nt++) *(float4v*)red[1][nt][lane] = acc[nt];
            }
        }
        __syncthreads();

        // ---- wave0: cell update + tagged publish (fire-and-forget, no drain) ----
        if (wv == 0) {
            #pragma unroll
            for (int nt = 0; nt < 4; nt++) acc[nt] += *(const float4v*)red[1][nt][lane];

            unsigned* ring = LAYER ? h2r : h1r;
            int slotW = t & (RB - 1);
            unsigned gen = (unsigned)t >> 5;      // 0..15, unique per run
            #pragma unroll
            for (int r = 0; r < 4; r++) {
                float ig  = acc[0][r] + bs[0];
                float fgt = acc[1][r] + bs[1];
                float zg  = acc[2][r] + bs[2];
                float og  = acc[3][r] + bs[3];
                float zc = fminf(fmaxf(zg, -15.f), 15.f);
                float e2 = __expf(2.f * zc);
                float zt = (e2 - 1.f) / (e2 + 1.f);
                float ot = 1.f / (1.f + __expf(-og));
                float mt = fmaxf(fgt + mst[r], ig);
                float it = __expf(ig - mt);
                float ft = __expf(fgt + mst[r] - mt);
                cst[r] = ft * cst[r] + it * zt;
                nst[r] = ft * nst[r] + it;
                mst[r] = mt;
                float h = ot * (cst[r] / nst[r]);
                int row = g * 16 + q * 4 + r;
                int col = slice * 16 + mrow;
                unsigned uh = __float_as_uint(h);
                uh = ((uh + 16u) & ~31u) | gen;   // round mantissa to multiple of 32, tag
                st_cg_u32(ring + ((size_t)slotW * NBATCH + row) * HID + col, uh);
                if (LAYER == 1 && t == TSTEPS - 1)
                    st_cg_f32(hOut + (size_t)row * HID + col, h);
            }
        }
    }
}

__global__ __launch_bounds__(512, 2) void recur(
    const float* __restrict__ x,
    int* flags, const float* bias,
    unsigned* h1r, unsigned* h2r, const ushort_t* wf1, const ushort_t* wf2, float* hOut)
{
    __shared__ ushort_t sA[16 * 520];
    __shared__ ushort_t sB[16 * 520];
    __shared__ float red[8][4][64][4];
    int g = blockIdx.x & 7;
    int loc = blockIdx.x >> 3;
    if (loc < 16)
        run_layer<0, 4, 10, 328>(g, loc, threadIdx.x, x, flags, bias, h1r, h2r, wf1, hOut, sA, sB, red);
    else
        run_layer<1, 6, 16, 520>(g, loc - 16, threadIdx.x, x, flags, bias, h1r, h2r, wf2, hOut, sA, sB, red);
}

// ---------------- head MLP ----------------

__global__ void head_mlp(const float* hOut, const float* W1, const float* b1,
                         const float* W2, const float* b2, const float* W3, const float* b3,
                         float* out)
{
    __shared__ float h[256];
    __shared__ float a1[128];
    __shared__ float a2[64];
    int b = blockIdx.x, j = threadIdx.x;
    for (int k = j; k < 256; k += 128)
        h[k] = ld_cg_f32(hOut + (size_t)b * HID + k);
    __syncthreads();
    float s = b1[j];
    for (int k = 0; k < 256; k++) s += W1[j * 256 + k] * h[k];
    a1[j] = fmaxf(s, 0.f);
    __syncthreads();
    if (j < 64) {
        float s2 = b2[j];
        for (int k = 0; k < 128; k++) s2 += W2[j * 128 + k] * a1[k];
        a2[j] = fmaxf(s2, 0.f);
    }
    __syncthreads();
    if (j == 0) {
        float s3 = b3[0];
        for (int k = 0; k < 64; k++) s3 += W3[k] * a2[k];
        out[b] = s3;
    }
}

// ---------------- launch ----------------

extern "C" void kernel_launch(void* const* d_in, const int* in_sizes, int n_in,
                              void* d_out, int out_size, void* d_ws, size_t ws_size,
                              hipStream_t stream)
{
    const float* x    = (const float*)d_in[0];
    const float* Wxh1 = (const float*)d_in[1];
    const float* bxh1 = (const float*)d_in[2];
    const float* Whh1 = (const float*)d_in[3];
    const float* bhh1 = (const float*)d_in[4];
    const float* Wxh2 = (const float*)d_in[5];
    const float* bxh2 = (const float*)d_in[6];
    const float* Whh2 = (const float*)d_in[7];
    const float* bhh2 = (const float*)d_in[8];
    const float* W1   = (const float*)d_in[9];
    const float* b1   = (const float*)d_in[10];
    const float* W2   = (const float*)d_in[11];
    const float* b2   = (const float*)d_in[12];
    const float* W3   = (const float*)d_in[13];
    const float* b3   = (const float*)d_in[14];

    char* w = (char*)d_ws;
    int*      flags = (int*)(w + OFF_FLAGS);
    float*    bias  = (float*)(w + OFF_BIAS);
    unsigned* h1r   = (unsigned*)(w + OFF_H1R);
    unsigned* h2r   = (unsigned*)(w + OFF_H2R);
    ushort_t* wf1   = (ushort_t*)(w + OFF_WF1);
    ushort_t* wf2   = (ushort_t*)(w + OFF_WF2);
    float*    hOut  = (float*)(w + OFF_HOUT);

    prep_misc<<<(2304 + 2 * RING_DW + 255) / 256, 256, 0, stream>>>(bxh1, bhh1, bxh2, bhh2,
                                                                    bias, flags, h1r, h2r);
    prep_wf<<<((WF1_FRAGS + WF2_FRAGS) * 512 + 255) / 256, 256, 0, stream>>>(
        Wxh1, Whh1, Wxh2, Whh2, wf1, wf2);

    const float* xp = x;
    void* args[] = { (void*)&xp, (void*)&flags, (void*)&bias,
                     (void*)&h1r, (void*)&h2r, (void*)&wf1, (void*)&wf2, (void*)&hOut };
    hipLaunchCooperativeKernel((void*)recur, dim3(256), dim3(512), args, 0, stream);

    head_mlp<<<NBATCH, 128, 0, stream>>>(hOut, W1, b1, W2, b2, W3, b3, (float*)d_out);
}